// Round 6
// baseline (144.747 us; speedup 1.0000x reference)
//
#include <hip/hip_runtime.h>
#include <hip/hip_cooperative_groups.h>
#include <cfloat>

namespace cg = cooperative_groups;

#define NEG_INF_F (-1e30f)

constexpr int BB = 8, SS = 4096, HH = 1024;
constexpr int TOTAL = BB * SS;   // 32768 rows
constexpr int MAXLEN = 30;
constexpr int TPB = 256;
constexpr int CGRID = 512;       // 2 blocks/CU co-residency needed (wide margin)

// ---------------- top-5 helpers ----------------
__device__ __forceinline__ bool t5_better(float av, int ai, float bv, int bi) {
  // jax top_k tie-break: lower flat index wins on equal value
  return av > bv || (av == bv && ai < bi);
}

// Sorted-descending 5-list insert; all indices compile-time (no scratch).
__device__ __forceinline__ void t5_insert(float v[5], int id[5], float nv, int ni) {
  if (!t5_better(nv, ni, v[4], id[4])) return;
  v[4] = nv; id[4] = ni;
#pragma unroll
  for (int q = 4; q > 0; --q) {
    if (t5_better(v[q], id[q], v[q - 1], id[q - 1])) {
      float tv = v[q]; v[q] = v[q - 1]; v[q - 1] = tv;
      int ti = id[q]; id[q] = id[q - 1]; id[q - 1] = ti;
    }
  }
}

__device__ __forceinline__ void t5_init(float v[5], int id[5]) {
#pragma unroll
  for (int q = 0; q < 5; ++q) { v[q] = -FLT_MAX; id[q] = 0x7fffffff; }
}

// Wave-wide top-5 via 5 argmax rounds; result identical in every lane.
__device__ __forceinline__ void wave_top5(float v[5], int id[5],
                                          float rv[5], int rid[5]) {
#pragma unroll
  for (int r = 0; r < 5; ++r) {
    float bv = v[0]; int bi = id[0];
#pragma unroll
    for (int q = 1; q < 5; ++q)
      if (t5_better(v[q], id[q], bv, bi)) { bv = v[q]; bi = id[q]; }
#pragma unroll
    for (int off = 1; off < 64; off <<= 1) {
      float ov = __shfl_xor(bv, off);
      int oi = __shfl_xor(bi, off);
      if (t5_better(ov, oi, bv, bi)) { bv = ov; bi = oi; }
    }
    rv[r] = bv; rid[r] = bi;
#pragma unroll
    for (int q = 0; q < 5; ++q)
      if (id[q] == bi) v[q] = -FLT_MAX;  // ids unique; sentinels all -FLT_MAX anyway
  }
}

// ---------------- single cooperative kernel ----------------
// Phase A: GEMV+mask (grid-stride, one wave/row)
// sync
// Phase B1: banded top-5, 4 threads/row (8 candidates each), block-top5 -> ws
// sync
// Phase B2: blocks 0..7 merge their batch's 64 block-results (320 candidates)
__global__ __launch_bounds__(TPB) void fused_answerer(
    const float* __restrict__ X,     // (B*S, H)
    const float* __restrict__ mask,  // (B*S)
    const float* __restrict__ W,     // (H, 2) row-major
    const float* __restrict__ bqa,   // (2)
    float* __restrict__ out,         // start | end | top_start | top_end
    float* __restrict__ wv_ws,       // (CGRID, 5)
    int* __restrict__ wi_ws) {       // (CGRID, 5)
  const int lane = threadIdx.x & 63;
  const int wid = blockIdx.x * (TPB / 64) + ((int)threadIdx.x >> 6);
  const int nwaves = CGRID * (TPB / 64);
  const float b0 = bqa[0], b1 = bqa[1];

  // ---------- Phase A: GEMV (measured roofline ~20 us @ 6.7 TB/s) ----------
  for (int row = wid; row < TOTAL; row += nwaves) {
    const float* rp = X + (size_t)row * HH;
    float s0 = 0.f, s1 = 0.f;
#pragma unroll
    for (int k = 0; k < HH / 256; ++k) {
      int h = (k * 64 + lane) * 4;
      const float4 x   = *reinterpret_cast<const float4*>(rp + h);
      const float4 w01 = *reinterpret_cast<const float4*>(W + 2 * h);
      const float4 w23 = *reinterpret_cast<const float4*>(W + 2 * h + 4);
      s0 += x.x * w01.x + x.y * w01.z + x.z * w23.x + x.w * w23.z;
      s1 += x.x * w01.y + x.y * w01.w + x.z * w23.y + x.w * w23.w;
    }
#pragma unroll
    for (int off = 32; off > 0; off >>= 1) {
      s0 += __shfl_down(s0, off);
      s1 += __shfl_down(s1, off);
    }
    if (lane == 0) {
      float m = mask[row];
      float inv = 1.f - m;
      out[row]         = (s0 + b0) * m + inv * NEG_INF_F;
      out[TOTAL + row] = (s1 + b1) * m + inv * NEG_INF_F;
    }
  }

  cg::this_grid().sync();

  // ---------- Phase B1: banded top-5, 4 threads per row ----------
  // gtid -> (row = gtid/4, sub = gtid%4); sub covers candidates [8*sub, 8*sub+8)
  {
    int gtid = blockIdx.x * TPB + (int)threadIdx.x;
    int row = gtid >> 2;
    int sub = gtid & 3;
    int b = row >> 12;          // row / 4096
    int i = row & (SS - 1);     // row % 4096
    const float* en = out + TOTAL + (size_t)b * SS;

    float v[5]; int id[5];
    t5_init(v, id);

    if (i >= 4) {
      float si = out[row];
      int c0 = sub * 8;
      float e[8];
#pragma unroll
      for (int c = 0; c < 8; ++c) {
        int cc = c0 + c, j = i + cc;
        e[c] = (cc < MAXLEN && j < SS) ? en[j] : NEG_INF_F;
      }
      int base = i * SS + i + c0;
#pragma unroll
      for (int c = 0; c < 8; ++c) t5_insert(v, id, si + e[c], base + c);
    } else if (i >= 1 && sub == 0) {
      t5_insert(v, id, out[row] + en[i], i * SS + i);  // (1,1),(2,2),(3,3)
    }

    float rv[5]; int rid[5];
    wave_top5(v, id, rv, rid);

    __shared__ float sv[(TPB / 64) * 5];
    __shared__ int   sid[(TPB / 64) * 5];
    int w = (int)threadIdx.x >> 6;
    if (lane == 0) {
#pragma unroll
      for (int q = 0; q < 5; ++q) { sv[w * 5 + q] = rv[q]; sid[w * 5 + q] = rid[q]; }
    }
    __syncthreads();
    if (w == 0) {
      float fv[5]; int fid[5];
      t5_init(fv, fid);
      if (lane < (TPB / 64) * 5) t5_insert(fv, fid, sv[lane], sid[lane]);
      float gv[5]; int gid[5];
      wave_top5(fv, fid, gv, gid);
      if (lane == 0) {
#pragma unroll
        for (int q = 0; q < 5; ++q) {
          wv_ws[blockIdx.x * 5 + q] = gv[q];
          wi_ws[blockIdx.x * 5 + q] = gid[q];
        }
      }
    }
  }

  cg::this_grid().sync();

  // ---------- Phase B2: per-batch final merge (64 blocks * 5 = 320) ----------
  if (blockIdx.x < (unsigned)BB && threadIdx.x < 64) {
    int b = blockIdx.x;
    float fv[5]; int fid[5];
    t5_init(fv, fid);
#pragma unroll
    for (int q = 0; q < 5; ++q) {
      int c = b * 320 + lane * 5 + q;
      t5_insert(fv, fid, wv_ws[c], wi_ws[c]);
    }
    float gv[5]; int gid[5];
    wave_top5(fv, fid, gv, gid);
    if (lane == 0) {
      float* ts = out + 2 * (size_t)TOTAL;
      float* te = ts + BB * 5;
#pragma unroll
      for (int q = 0; q < 5; ++q) {
        ts[b * 5 + q] = (float)(gid[q] >> 12);       // id / S  (S=4096)
        te[b * 5 + q] = (float)(gid[q] & (SS - 1));  // id % S
      }
    }
  }
}

// ---------------- fallback path (R3 structure, proven correct) ----------------
__global__ __launch_bounds__(256) void qa_logits_kernel(
    const float* __restrict__ X, const float* __restrict__ mask,
    const float* __restrict__ W, const float* __restrict__ bqa,
    float* __restrict__ out) {
  int row  = (int)((blockIdx.x * (size_t)blockDim.x + threadIdx.x) >> 6);
  int lane = threadIdx.x & 63;
  if (row >= TOTAL) return;
  const float* rp = X + (size_t)row * HH;
  float s0 = 0.f, s1 = 0.f;
#pragma unroll
  for (int k = 0; k < HH / 256; ++k) {
    int h = (k * 64 + lane) * 4;
    const float4 x   = *reinterpret_cast<const float4*>(rp + h);
    const float4 w01 = *reinterpret_cast<const float4*>(W + 2 * h);
    const float4 w23 = *reinterpret_cast<const float4*>(W + 2 * h + 4);
    s0 += x.x * w01.x + x.y * w01.z + x.z * w23.x + x.w * w23.z;
    s1 += x.x * w01.y + x.y * w01.w + x.z * w23.y + x.w * w23.w;
  }
#pragma unroll
  for (int off = 32; off > 0; off >>= 1) {
    s0 += __shfl_down(s0, off);
    s1 += __shfl_down(s1, off);
  }
  if (lane == 0) {
    float m = mask[row];
    float inv = 1.f - m;
    out[row]         = (s0 + bqa[0]) * m + inv * NEG_INF_F;
    out[TOTAL + row] = (s1 + bqa[1]) * m + inv * NEG_INF_F;
  }
}

__global__ __launch_bounds__(64) void topk_stage1(
    const float* __restrict__ logits, float* __restrict__ wv_out,
    int* __restrict__ wi_out) {
  int blocks_per_b = SS / 64;
  int b  = blockIdx.x / blocks_per_b;
  int rb = blockIdx.x % blocks_per_b;
  int lane = (int)threadIdx.x;
  int i = rb * 64 + lane;
  const float* st = logits + (size_t)b * SS;
  const float* en = logits + (size_t)(BB + b) * SS;
  float v[5]; int id[5];
  t5_init(v, id);
  if (i >= 4) {
    float si = st[i];
    float e[MAXLEN];
#pragma unroll
    for (int c = 0; c < MAXLEN; ++c) {
      int j = i + c;
      e[c] = (j < SS) ? en[j] : NEG_INF_F;
    }
    int base = i * SS + i;
#pragma unroll
    for (int c = 0; c < MAXLEN; ++c) t5_insert(v, id, si + e[c], base + c);
  } else if (i >= 1) {
    t5_insert(v, id, st[i] + en[i], i * SS + i);
  }
  float rv[5]; int rid[5];
  wave_top5(v, id, rv, rid);
  if (lane == 0) {
#pragma unroll
    for (int q = 0; q < 5; ++q) {
      wv_out[blockIdx.x * 5 + q] = rv[q];
      wi_out[blockIdx.x * 5 + q] = rid[q];
    }
  }
}

__global__ __launch_bounds__(64) void topk_stage2(
    const float* __restrict__ wv_in, const int* __restrict__ wi_in,
    float* __restrict__ out) {
  int b = blockIdx.x;
  int lane = (int)threadIdx.x;
  int n = (SS / 64) * 5;  // 320
  const float* wv = wv_in + (size_t)b * n;
  const int*   wi = wi_in + (size_t)b * n;
  float v[5]; int id[5];
  t5_init(v, id);
#pragma unroll 5
  for (int c = lane; c < n; c += 64) t5_insert(v, id, wv[c], wi[c]);
  float rv[5]; int rid[5];
  wave_top5(v, id, rv, rid);
  if (lane == 0) {
    float* ts = out + 2 * (size_t)TOTAL;
    float* te = ts + BB * 5;
#pragma unroll
    for (int q = 0; q < 5; ++q) {
      ts[b * 5 + q] = (float)(rid[q] >> 12);
      te[b * 5 + q] = (float)(rid[q] & (SS - 1));
    }
  }
}

extern "C" void kernel_launch(void* const* d_in, const int* in_sizes, int n_in,
                              void* d_out, int out_size, void* d_ws, size_t ws_size,
                              hipStream_t stream) {
  const float* X    = (const float*)d_in[0];  // (B,S,H)
  const float* mask = (const float*)d_in[1];  // (B,S)
  const float* W    = (const float*)d_in[2];  // (H,2)
  const float* bqa  = (const float*)d_in[3];  // (2)
  float* out = (float*)d_out;
  float* wv_ws = (float*)d_ws;
  int*   wi_ws = (int*)((char*)d_ws + (size_t)CGRID * 5 * sizeof(float));

  void* args[] = {(void*)&X, (void*)&mask, (void*)&W, (void*)&bqa,
                  (void*)&out, (void*)&wv_ws, (void*)&wi_ws};
  hipError_t err = hipLaunchCooperativeKernel((const void*)fused_answerer,
                                              dim3(CGRID), dim3(TPB), args, 0, stream);
  if (err != hipSuccess) {
    // Fallback: proven 3-kernel path (R3). Same numerics, ~42 us.
    qa_logits_kernel<<<TOTAL / 4, 256, 0, stream>>>(X, mask, W, bqa, out);
    topk_stage1<<<BB * (SS / 64), 64, 0, stream>>>(out, wv_ws, wi_ws);
    topk_stage2<<<BB, 64, 0, stream>>>(wv_ws, wi_ws, out);
  }
}

// Round 7
// 47.593 us; speedup vs baseline: 3.0413x; 3.0413x over previous
//
#include <hip/hip_runtime.h>
#include <cfloat>

#define NEG_INF_F (-1e30f)

constexpr int BB = 8, SS = 4096, HH = 1024;
constexpr int TOTAL = BB * SS;     // 32768 rows
constexpr int MAXLEN = 30;
constexpr int TKB = 512;           // topk blocks; 64 rows per block
constexpr int BLK_PER_B = TKB / BB;  // 64 blocks per batch

// ---------------- top-5 helpers ----------------
__device__ __forceinline__ bool t5_better(float av, int ai, float bv, int bi) {
  // jax top_k tie-break: lower flat index wins on equal value
  return av > bv || (av == bv && ai < bi);
}

__device__ __forceinline__ void t5_insert(float v[5], int id[5], float nv, int ni) {
  if (!t5_better(nv, ni, v[4], id[4])) return;
  v[4] = nv; id[4] = ni;
#pragma unroll
  for (int q = 4; q > 0; --q) {
    if (t5_better(v[q], id[q], v[q - 1], id[q - 1])) {
      float tv = v[q]; v[q] = v[q - 1]; v[q - 1] = tv;
      int ti = id[q]; id[q] = id[q - 1]; id[q - 1] = ti;
    }
  }
}

__device__ __forceinline__ void t5_init(float v[5], int id[5]) {
#pragma unroll
  for (int q = 0; q < 5; ++q) { v[q] = -FLT_MAX; id[q] = 0x7fffffff; }
}

// Wave-wide top-5 via 5 argmax rounds; result identical in every lane.
__device__ __forceinline__ void wave_top5(float v[5], int id[5],
                                          float rv[5], int rid[5]) {
#pragma unroll
  for (int r = 0; r < 5; ++r) {
    float bv = v[0]; int bi = id[0];
#pragma unroll
    for (int q = 1; q < 5; ++q)
      if (t5_better(v[q], id[q], bv, bi)) { bv = v[q]; bi = id[q]; }
#pragma unroll
    for (int off = 1; off < 64; off <<= 1) {
      float ov = __shfl_xor(bv, off);
      int oi = __shfl_xor(bi, off);
      if (t5_better(ov, oi, bv, bi)) { bv = ov; bi = oi; }
    }
    rv[r] = bv; rid[r] = bi;
#pragma unroll
    for (int q = 0; q < 5; ++q)
      if (id[q] == bi) v[q] = -FLT_MAX;  // candidate ids are unique
  }
}

// ---------------- Kernel 1: QA-head GEMV + masking ----------------
// One wave per row, no inner loop -> 12 loads in flight per wave, 8192 blocks
// -> full occupancy. Measured at BW roofline (~6.7 TB/s) in R1-R3.
// Also zeroes the topk ticket counters (block 0) so every replay is clean.
__global__ __launch_bounds__(256) void qa_logits_kernel(
    const float* __restrict__ X,     // (B*S, H)
    const float* __restrict__ mask,  // (B*S)
    const float* __restrict__ W,     // (H, 2) row-major
    const float* __restrict__ bqa,   // (2)
    float* __restrict__ out,         // [0,TOTAL): start, [TOTAL,2*TOTAL): end
    int* __restrict__ counters) {    // (BB) ticket counters
  if (blockIdx.x == 0 && threadIdx.x < BB) counters[threadIdx.x] = 0;
  int row  = (int)((blockIdx.x * (size_t)blockDim.x + threadIdx.x) >> 6);
  int lane = threadIdx.x & 63;
  if (row >= TOTAL) return;
  const float* rp = X + (size_t)row * HH;
  float s0 = 0.f, s1 = 0.f;
#pragma unroll
  for (int k = 0; k < HH / 256; ++k) {
    int h = (k * 64 + lane) * 4;
    const float4 x   = *reinterpret_cast<const float4*>(rp + h);
    const float4 w01 = *reinterpret_cast<const float4*>(W + 2 * h);
    const float4 w23 = *reinterpret_cast<const float4*>(W + 2 * h + 4);
    s0 += x.x * w01.x + x.y * w01.z + x.z * w23.x + x.w * w23.z;
    s1 += x.x * w01.y + x.y * w01.w + x.z * w23.y + x.w * w23.w;
  }
#pragma unroll
  for (int off = 32; off > 0; off >>= 1) {
    s0 += __shfl_down(s0, off);
    s1 += __shfl_down(s1, off);
  }
  if (lane == 0) {
    float m = mask[row];
    float inv = 1.f - m;
    out[row]         = (s0 + bqa[0]) * m + inv * NEG_INF_F;
    out[TOTAL + row] = (s1 + bqa[1]) * m + inv * NEG_INF_F;
  }
}

// ---------------- Kernel 2: banded top-5, single launch ----------------
// 512 blocks x 256 threads; 4 threads per row, 8 candidates each.
// Block merge -> 5 results -> agent-scope stores to ws -> threadfence ->
// per-batch ticket; the last block of each batch merges 64x5 = 320 candidates.
__global__ __launch_bounds__(256) void topk_kernel(
    const float* __restrict__ logits,  // gemv output (start then end)
    float* __restrict__ out,
    float* __restrict__ wv_ws,         // (TKB, 5)
    int* __restrict__ wi_ws,           // (TKB, 5)
    int* __restrict__ counters) {      // (BB)
  const int lane = threadIdx.x & 63;
  const int w = (int)threadIdx.x >> 6;
  const int b = blockIdx.x / BLK_PER_B;  // 64 rows/block -> 64 blocks/batch

  // ---- per-thread scan: row = gtid/4, sub = gtid%4 covers 8 candidates ----
  int gtid = blockIdx.x * 256 + (int)threadIdx.x;
  int row = gtid >> 2;
  int sub = gtid & 3;
  int i = row & (SS - 1);
  const float* en = logits + TOTAL + (size_t)b * SS;

  float v[5]; int id[5];
  t5_init(v, id);

  if (i >= 4) {
    float si = logits[row];
    int c0 = sub * 8;
    float e[8];
#pragma unroll
    for (int c = 0; c < 8; ++c) {
      int cc = c0 + c, j = i + cc;
      e[c] = (cc < MAXLEN && j < SS) ? en[j] : NEG_INF_F;  // loads before inserts
    }
    int base = i * SS + i + c0;
#pragma unroll
    for (int c = 0; c < 8; ++c) t5_insert(v, id, si + e[c], base + c);
  } else if (i >= 1 && sub == 0) {
    t5_insert(v, id, logits[row] + en[i], i * SS + i);  // (1,1),(2,2),(3,3)
  }

  float rv[5]; int rid[5];
  wave_top5(v, id, rv, rid);

  __shared__ float sv[(256 / 64) * 5];
  __shared__ int   sid[(256 / 64) * 5];
  if (lane == 0) {
#pragma unroll
    for (int q = 0; q < 5; ++q) { sv[w * 5 + q] = rv[q]; sid[w * 5 + q] = rid[q]; }
  }
  __syncthreads();

  if (w == 0) {
    // ---- block merge: 4 waves * 5 = 20 candidates ----
    float fv[5]; int fid[5];
    t5_init(fv, fid);
    if (lane < 20) t5_insert(fv, fid, sv[lane], sid[lane]);
    float gv[5]; int gid[5];
    wave_top5(fv, fid, gv, gid);

    // ---- publish block result + ticket ----
    int old = -1;
    if (lane == 0) {
#pragma unroll
      for (int q = 0; q < 5; ++q) {
        __hip_atomic_store(&wv_ws[blockIdx.x * 5 + q], gv[q],
                           __ATOMIC_RELAXED, __HIP_MEMORY_SCOPE_AGENT);
        __hip_atomic_store(&wi_ws[blockIdx.x * 5 + q], gid[q],
                           __ATOMIC_RELAXED, __HIP_MEMORY_SCOPE_AGENT);
      }
      __threadfence();  // release: block result visible before ticket
      old = atomicAdd(&counters[b], 1);
    }
    old = __shfl(old, 0);

    if (old == BLK_PER_B - 1) {  // last block of this batch
      __threadfence();           // acquire: other blocks' results visible
      float hv[5]; int hid[5];
      t5_init(hv, hid);
      int blk = b * BLK_PER_B + lane;  // lane < 64 == BLK_PER_B
#pragma unroll
      for (int q = 0; q < 5; ++q) {
        float cv = __hip_atomic_load(&wv_ws[blk * 5 + q],
                                     __ATOMIC_RELAXED, __HIP_MEMORY_SCOPE_AGENT);
        int ci = __hip_atomic_load(&wi_ws[blk * 5 + q],
                                   __ATOMIC_RELAXED, __HIP_MEMORY_SCOPE_AGENT);
        t5_insert(hv, hid, cv, ci);
      }
      float kv[5]; int kid[5];
      wave_top5(hv, hid, kv, kid);
      if (lane == 0) {
        float* ts = out + 2 * (size_t)TOTAL;  // top_start region
        float* te = ts + BB * 5;              // top_end region
#pragma unroll
        for (int q = 0; q < 5; ++q) {
          ts[b * 5 + q] = (float)(kid[q] >> 12);       // id / S  (S=4096)
          te[b * 5 + q] = (float)(kid[q] & (SS - 1));  // id % S
        }
      }
    }
  }
}

extern "C" void kernel_launch(void* const* d_in, const int* in_sizes, int n_in,
                              void* d_out, int out_size, void* d_ws, size_t ws_size,
                              hipStream_t stream) {
  const float* X    = (const float*)d_in[0];  // (B,S,H)
  const float* mask = (const float*)d_in[1];  // (B,S)
  const float* W    = (const float*)d_in[2];  // (H,2)
  const float* bqa  = (const float*)d_in[3];  // (2)
  float* out = (float*)d_out;

  float* wv_ws = (float*)d_ws;                                   // TKB*5 floats
  int*   wi_ws = (int*)((char*)d_ws + TKB * 5 * sizeof(float));  // TKB*5 ints
  int*   counters = (int*)((char*)d_ws + 2 * TKB * 5 * sizeof(float));  // BB ints

  qa_logits_kernel<<<TOTAL / 4, 256, 0, stream>>>(X, mask, W, bqa, out, counters);
  topk_kernel<<<TKB, 256, 0, stream>>>(out, out, wv_ws, wi_ws, counters);
}